// Round 6
// baseline (764.051 us; speedup 1.0000x reference)
//
#include <hip/hip_runtime.h>
#include <hip/hip_bf16.h>

#define KC   1024
#define DD   256
#define NN   32768
#define HWC  1024
#define LOSS_OFF 8388608
#define IDX_OFF  8388609

// Replicate numpy pairwise_sum of a[i]*a[i], n=256 (validated: absmax 0.0 r2/r4/r5).
__device__ __forceinline__ float np_pairwise_sumsq_256(const float* __restrict__ a) {
#pragma clang fp contract(off)
  float half0, half1;
  {
    const float* p = a;
    float r[8];
#pragma unroll
    for (int j = 0; j < 8; ++j) r[j] = p[j] * p[j];
    for (int i = 8; i < 128; i += 8) {
#pragma unroll
      for (int j = 0; j < 8; ++j) r[j] = r[j] + p[i + j] * p[i + j];
    }
    half0 = ((r[0] + r[1]) + (r[2] + r[3])) + ((r[4] + r[5]) + (r[6] + r[7]));
  }
  {
    const float* p = a + 128;
    float r[8];
#pragma unroll
    for (int j = 0; j < 8; ++j) r[j] = p[j] * p[j];
    for (int i = 8; i < 128; i += 8) {
#pragma unroll
      for (int j = 0; j < 8; ++j) r[j] = r[j] + p[i + j] * p[i + j];
    }
    half1 = ((r[0] + r[1]) + (r[2] + r[3])) + ((r[4] + r[5]) + (r[6] + r[7]));
  }
  return half0 + half1;
}

// K0: e_sq[k] via numpy-pairwise; zero loss accumulator.
__global__ void vq_esq_kernel(const float* __restrict__ cb, float* __restrict__ esq,
                              float* __restrict__ loss_acc) {
  const int k = blockIdx.x * 256 + threadIdx.x;
  if (k == 0) loss_acc[0] = 0.0f;
  if (k < KC) esq[k] = np_pairwise_sumsq_256(cb + ((size_t)k << 8));
}

// K1: fused distance + argmin, thread=code layout.
// Block = 1024 threads (16 waves) x 64 rows, covering ALL 1024 codes:
//   wave w: row-group rg=w&3 (rows rg*16..+16), code-set cs=w>>2 (codes cs*256..+256)
//   thread: 4 codes c_j = cs*256 + j*64 + lane, j=0..3 (ascending k for fixed lane)
// Codebook -> VGPRs via global loads (vmcnt); x-tile -> wave-uniform broadcast
// ds_read_b128 (lgkmcnt, no SMEM mixing -> no conservative lgkmcnt(0) drains).
// ds:FMA instr ratio 1/16 => LDS pipe (<=196Kcyc/CU) under the 262Kcyc FMA window.
__global__ __launch_bounds__(1024)
void vq_argmin_kernel(const float* __restrict__ x, const float* __restrict__ cb,
                      const float* __restrict__ esq, int* __restrict__ idxout,
                      float* __restrict__ out) {
  __shared__ float xs[64][260];    // +pad keeps rows 16B aligned
  __shared__ float xsq[64];
  __shared__ float rbest[16][64];
  __shared__ int   rbidx[16][64];

  const int tid  = threadIdx.x;
  const int lane = tid & 63;
  const int w    = tid >> 6;          // 0..15
  const int rg   = w & 3;             // row group
  const int cs   = w >> 2;            // code set
  const int n0   = blockIdx.x << 6;   // 512 blocks x 64 rows
  const int b    = n0 >> 10;
  const int hw0  = n0 & 1023;
  const float* __restrict__ xb = x + (size_t)b * (DD * HWC) + hw0;

  // Stage x tile: xs[n][d] = x[b, d, hw0+n]; 16 waves x 16 d-columns, coalesced.
#pragma unroll
  for (int i = 0; i < 16; ++i) {
    const int d = (w << 4) + i;
    xs[lane][d] = xb[(size_t)d * HWC + lane];
  }
  __syncthreads();

  // x_sq per row, numpy-pairwise bitwise (tie reproduction — do not change).
  if (tid < 64) xsq[tid] = np_pairwise_sumsq_256(&xs[tid][0]);
  __syncthreads();

  const int c0 = (cs << 8) + lane;
  const float* __restrict__ e0p = cb + ((size_t)c0 << 8);
  const int r0 = rg << 4;

  float acc[4][16];
#pragma unroll
  for (int j = 0; j < 4; ++j)
#pragma unroll
    for (int r = 0; r < 16; ++r) acc[j][r] = 0.0f;

  // 64 chunks x 4 dims. Per chunk: 4 global float4 (own codes, L2-resident) +
  // 16 broadcast ds_read_b128 + 256 FMAs. d ascending => same fmaf chain order
  // as the validated r2 kernel.
  for (int ch = 0; ch < 64; ++ch) {
    float4 ev[4];
#pragma unroll
    for (int j = 0; j < 4; ++j)
      ev[j] = *(const float4*)(e0p + (j << 14) + (ch << 2));   // j*64 codes * 256 floats
#pragma unroll
    for (int r = 0; r < 16; ++r) {
      const float4 xv = *(const float4*)&xs[r0 + r][ch << 2];  // uniform addr -> broadcast
#pragma unroll
      for (int j = 0; j < 4; ++j) {
        acc[j][r] = fmaf(xv.x, ev[j].x, acc[j][r]);
        acc[j][r] = fmaf(xv.y, ev[j].y, acc[j][r]);
        acc[j][r] = fmaf(xv.z, ev[j].z, acc[j][r]);
        acc[j][r] = fmaf(xv.w, ev[j].w, acc[j][r]);
      }
    }
  }

  const float eq0 = esq[c0];
  const float eq1 = esq[c0 + 64];
  const float eq2 = esq[c0 + 128];
  const float eq3 = esq[c0 + 192];

#pragma unroll
  for (int r = 0; r < 16; ++r) {
    const float xq = xsq[r0 + r];
    float v; int ki;
    {
      // Reference rounding: fl(e_sq - fl(2*dot)) then fl(t + x_sq). No FMA here.
#pragma clang fp contract(off)
      const float d0 = (eq0 - 2.0f * acc[0][r]) + xq;
      const float d1 = (eq1 - 2.0f * acc[1][r]) + xq;
      const float d2 = (eq2 - 2.0f * acc[2][r]) + xq;
      const float d3 = (eq3 - 2.0f * acc[3][r]) + xq;
      v = d0; ki = c0;                                   // ascending k, strict <
      if (d1 < v) { v = d1; ki = c0 + 64; }
      if (d2 < v) { v = d2; ki = c0 + 128; }
      if (d3 < v) { v = d3; ki = c0 + 192; }
    }
    // Wave-wide (val,idx) min, lowest k on ties.
#pragma unroll
    for (int off = 32; off >= 1; off >>= 1) {
      const float v2 = __shfl_xor(v, off, 64);
      const int   k2 = __shfl_xor(ki, off, 64);
      if (v2 < v || (v2 == v && k2 < ki)) { v = v2; ki = k2; }
    }
    if (lane == 0) { rbest[w][r0 + r] = v; rbidx[w][r0 + r] = ki; }
  }
  __syncthreads();

  // Cross-wave merge: for row r, waves {rg, rg+4, rg+8, rg+12} = code sets 0..3
  // ascending; strict < keeps lowest k.
  if (tid < 64) {
    const int r   = tid;
    const int rgr = r >> 4;
    float bb = rbest[rgr][r];
    int   bi = rbidx[rgr][r];
#pragma unroll
    for (int q = 1; q < 4; ++q) {
      const int ww = rgr + (q << 2);
      const float v = rbest[ww][r];
      if (v < bb) { bb = v; bi = rbidx[ww][r]; }
    }
    idxout[n0 + r] = bi;
    out[IDX_OFF + n0 + r] = (float)bi;       // fp32 index output
  }
}

// K2: gather codebook rows per block into LDS, write x_q_st (fp32), accumulate loss.
__global__ __launch_bounds__(256, 2)
void vq_gather_kernel(const float* __restrict__ x, const float* __restrict__ cb,
                      const int* __restrict__ idxin, float* __restrict__ loss_acc,
                      float* __restrict__ out) {
  __shared__ float qs[64][260];
  __shared__ int   idx_s[64];
  __shared__ float wr[4];

  const int tid  = threadIdx.x;
  const int lane = tid & 63;
  const int w    = tid >> 6;
  const int n0   = blockIdx.x << 6;
  const int b    = n0 >> 10;
  const int hw0  = n0 & 1023;

  if (tid < 64) idx_s[tid] = idxin[n0 + tid];
  __syncthreads();

  const float4* __restrict__ cb4 = (const float4*)cb;
  for (int r = w; r < 64; r += 4) {
    const int c = idx_s[r];
    const float4 v = cb4[((size_t)c << 6) + lane];  // coalesced 1KB row read per wave
    *(float4*)&qs[r][lane << 2] = v;
  }
  __syncthreads();

  float lsum = 0.f;
  const size_t obase = (size_t)b * (DD * HWC) + hw0 + lane;
  for (int i = 0; i < 64; ++i) {
    const int d = (w << 6) + i;
    const size_t o = obase + (size_t)d * HWC;
    const float q  = qs[lane][d];
    const float xv = x[o];
    {
#pragma clang fp contract(off)
      const float df = q - xv;           // fl(x_q - x)
      out[o] = xv + df;                  // x_q_st = fl(x + fl(x_q - x)), fp32
      lsum = fmaf(df, df, lsum);         // loss accumulation (loose threshold)
    }
  }

  for (int off = 32; off > 0; off >>= 1) lsum += __shfl_down(lsum, off, 64);
  if (lane == 0) wr[w] = lsum;
  __syncthreads();
  if (tid == 0) atomicAdd(loss_acc, (wr[0] + wr[1]) + (wr[2] + wr[3]));
}

// K3: loss = 1.5 * mean((x_q - x)^2), fp32
__global__ void vq_loss_kernel(const float* __restrict__ loss_acc,
                               float* __restrict__ out) {
  if (threadIdx.x == 0) {
    const float m = loss_acc[0] / 8388608.0f;
    out[LOSS_OFF] = m + 0.5f * m;
  }
}

extern "C" void kernel_launch(void* const* d_in, const int* in_sizes, int n_in,
                              void* d_out, int out_size, void* d_ws, size_t ws_size,
                              hipStream_t stream) {
  const float* x  = (const float*)d_in[0];   // [32,256,32,32] fp32
  const float* cb = (const float*)d_in[1];   // [1024,256] fp32
  float* out = (float*)d_out;                // [x_q_st | loss | indices] fp32

  float* esq      = (float*)d_ws;            // 1024 floats
  float* loss_acc = esq + 1024;              // 1 float (zeroed by K0 each call)
  int*   idxbuf   = (int*)(esq + 1040);      // 32768 ints

  hipLaunchKernelGGL(vq_esq_kernel,    dim3(4),    dim3(256),  0, stream, cb, esq, loss_acc);
  hipLaunchKernelGGL(vq_argmin_kernel, dim3(512),  dim3(1024), 0, stream, x, cb, esq, idxbuf, out);
  hipLaunchKernelGGL(vq_gather_kernel, dim3(512),  dim3(256),  0, stream, x, cb, idxbuf, loss_acc, out);
  hipLaunchKernelGGL(vq_loss_kernel,   dim3(1),    dim3(64),   0, stream, loss_acc, out);
}

// Round 7
// 560.115 us; speedup vs baseline: 1.3641x; 1.3641x over previous
//
#include <hip/hip_runtime.h>
#include <hip/hip_bf16.h>

#define KC   1024
#define DD   256
#define NN   32768
#define HWC  1024
#define LOSS_OFF 8388608
#define IDX_OFF  8388609

// Replicate numpy pairwise_sum of a[i]*a[i], n=256 (validated: absmax 0.0 r2/r4/r5/r6).
__device__ __forceinline__ float np_pairwise_sumsq_256(const float* __restrict__ a) {
#pragma clang fp contract(off)
  float half0, half1;
  {
    const float* p = a;
    float r[8];
#pragma unroll
    for (int j = 0; j < 8; ++j) r[j] = p[j] * p[j];
    for (int i = 8; i < 128; i += 8) {
#pragma unroll
      for (int j = 0; j < 8; ++j) r[j] = r[j] + p[i + j] * p[i + j];
    }
    half0 = ((r[0] + r[1]) + (r[2] + r[3])) + ((r[4] + r[5]) + (r[6] + r[7]));
  }
  {
    const float* p = a + 128;
    float r[8];
#pragma unroll
    for (int j = 0; j < 8; ++j) r[j] = p[j] * p[j];
    for (int i = 8; i < 128; i += 8) {
#pragma unroll
      for (int j = 0; j < 8; ++j) r[j] = r[j] + p[i + j] * p[i + j];
    }
    half1 = ((r[0] + r[1]) + (r[2] + r[3])) + ((r[4] + r[5]) + (r[6] + r[7]));
  }
  return half0 + half1;
}

// K0: e_sq[k] via numpy-pairwise; zero loss accumulator.
__global__ void vq_esq_kernel(const float* __restrict__ cb, float* __restrict__ esq,
                              float* __restrict__ loss_acc) {
  const int k = blockIdx.x * 256 + threadIdx.x;
  if (k == 0) loss_acc[0] = 0.0f;
  if (k < KC) esq[k] = np_pairwise_sumsq_256(cb + ((size_t)k << 8));
}

// K1: fused distance + argmin, thread=code layout, hosted in the proven
// 128-VGPR tier: 256-thread block (LB(256,2) — only config observed to give
// VGPR=128, r2), 16 rows/block, all 1024 codes.
//   wave w (0..3): codes [w*256, (w+1)*256); thread: 4 codes c_j = w*256+j*64+lane
//   acc[4][16] = 64 VGPRs; live set ~105 <= 128 -> no spill (r4/r6 pathology).
// Codebook -> VGPRs via per-lane global loads (vmcnt, L1/L2-resident);
// x-tile -> wave-uniform broadcast ds_read_b128 (lgkmcnt, no SMEM mixing).
__global__ __launch_bounds__(256, 2)
void vq_argmin_kernel(const float* __restrict__ x, const float* __restrict__ cb,
                      const float* __restrict__ esq, int* __restrict__ idxout,
                      float* __restrict__ out) {
  __shared__ float xs[16][260];    // 16 rows x 256 d (+pad, 16B-aligned rows)
  __shared__ float xsq[16];
  __shared__ float rbest[4][16];
  __shared__ int   rbidx[4][16];

  const int tid  = threadIdx.x;
  const int lane = tid & 63;
  const int w    = tid >> 6;          // 0..3 = code set
  const int n0   = blockIdx.x << 4;   // 2048 blocks x 16 rows
  const int b    = n0 >> 10;
  const int hw0  = n0 & 1023;
  const float* __restrict__ xb = x + (size_t)b * (DD * HWC) + hw0;

  // Stage x tile: xs[r][d] = x[b, d, hw0+r]. thread t: r = t&15, d = i*16 + (t>>4).
  // Each 16-thread group reads one 64B-aligned fully-used cache line.
  {
    const int rr = tid & 15;
    const int dq = tid >> 4;     // 0..15
#pragma unroll
    for (int i = 0; i < 16; ++i) {
      const int d = (i << 4) + dq;
      xs[rr][d] = xb[(size_t)d * HWC + rr];
    }
  }
  __syncthreads();

  // x_sq per row, numpy-pairwise bitwise (tie reproduction — do not change).
  if (tid < 16) xsq[tid] = np_pairwise_sumsq_256(&xs[tid][0]);
  __syncthreads();

  const int c0 = (w << 8) + lane;
  const float* __restrict__ e0p = cb + ((size_t)c0 << 8);

  float acc[4][16];
#pragma unroll
  for (int j = 0; j < 4; ++j)
#pragma unroll
    for (int r = 0; r < 16; ++r) acc[j][r] = 0.0f;

  // 64 chunks x 4 dims. Per chunk: 4 per-lane global float4 (own code rows,
  // L1-line reuse across ch) + 16 broadcast ds_read_b128 + 256 FMAs.
  for (int ch = 0; ch < 64; ++ch) {
    float4 ev[4];
#pragma unroll
    for (int j = 0; j < 4; ++j)
      ev[j] = *(const float4*)(e0p + (j << 14) + (ch << 2));   // j*64 codes * 256 floats
#pragma unroll
    for (int r = 0; r < 16; ++r) {
      const float4 xv = *(const float4*)&xs[r][ch << 2];       // uniform -> broadcast
#pragma unroll
      for (int j = 0; j < 4; ++j) {
        acc[j][r] = fmaf(xv.x, ev[j].x, acc[j][r]);
        acc[j][r] = fmaf(xv.y, ev[j].y, acc[j][r]);
        acc[j][r] = fmaf(xv.z, ev[j].z, acc[j][r]);
        acc[j][r] = fmaf(xv.w, ev[j].w, acc[j][r]);
      }
    }
  }

  const float eq0 = esq[c0];
  const float eq1 = esq[c0 + 64];
  const float eq2 = esq[c0 + 128];
  const float eq3 = esq[c0 + 192];

#pragma unroll
  for (int r = 0; r < 16; ++r) {
    const float xq = xsq[r];
    float v; int ki;
    {
      // Reference rounding: fl(e_sq - fl(2*dot)) then fl(t + x_sq). No FMA here.
#pragma clang fp contract(off)
      const float d0 = (eq0 - 2.0f * acc[0][r]) + xq;
      const float d1 = (eq1 - 2.0f * acc[1][r]) + xq;
      const float d2 = (eq2 - 2.0f * acc[2][r]) + xq;
      const float d3 = (eq3 - 2.0f * acc[3][r]) + xq;
      v = d0; ki = c0;                                   // ascending k, strict <
      if (d1 < v) { v = d1; ki = c0 + 64; }
      if (d2 < v) { v = d2; ki = c0 + 128; }
      if (d3 < v) { v = d3; ki = c0 + 192; }
    }
    // Wave-wide (val,idx) min, lowest k on ties.
#pragma unroll
    for (int off = 32; off >= 1; off >>= 1) {
      const float v2 = __shfl_xor(v, off, 64);
      const int   k2 = __shfl_xor(ki, off, 64);
      if (v2 < v || (v2 == v && k2 < ki)) { v = v2; ki = k2; }
    }
    if (lane == 0) { rbest[w][r] = v; rbidx[w][r] = ki; }
  }
  __syncthreads();

  // Cross-wave merge in ascending code-set order; strict < keeps lowest k.
  if (tid < 16) {
    float bb = rbest[0][tid];
    int   bi = rbidx[0][tid];
#pragma unroll
    for (int q = 1; q < 4; ++q) {
      const float v = rbest[q][tid];
      if (v < bb) { bb = v; bi = rbidx[q][tid]; }
    }
    idxout[n0 + tid] = bi;
    out[IDX_OFF + n0 + tid] = (float)bi;       // fp32 index output
  }
}

// K2: gather codebook rows per block into LDS, write x_q_st (fp32), accumulate loss.
__global__ __launch_bounds__(256, 2)
void vq_gather_kernel(const float* __restrict__ x, const float* __restrict__ cb,
                      const int* __restrict__ idxin, float* __restrict__ loss_acc,
                      float* __restrict__ out) {
  __shared__ float qs[64][260];
  __shared__ int   idx_s[64];
  __shared__ float wr[4];

  const int tid  = threadIdx.x;
  const int lane = tid & 63;
  const int w    = tid >> 6;
  const int n0   = blockIdx.x << 6;
  const int b    = n0 >> 10;
  const int hw0  = n0 & 1023;

  if (tid < 64) idx_s[tid] = idxin[n0 + tid];
  __syncthreads();

  const float4* __restrict__ cb4 = (const float4*)cb;
  for (int r = w; r < 64; r += 4) {
    const int c = idx_s[r];
    const float4 v = cb4[((size_t)c << 6) + lane];  // coalesced 1KB row read per wave
    *(float4*)&qs[r][lane << 2] = v;
  }
  __syncthreads();

  float lsum = 0.f;
  const size_t obase = (size_t)b * (DD * HWC) + hw0 + lane;
  for (int i = 0; i < 64; ++i) {
    const int d = (w << 6) + i;
    const size_t o = obase + (size_t)d * HWC;
    const float q  = qs[lane][d];
    const float xv = x[o];
    {
#pragma clang fp contract(off)
      const float df = q - xv;           // fl(x_q - x)
      out[o] = xv + df;                  // x_q_st = fl(x + fl(x_q - x)), fp32
      lsum = fmaf(df, df, lsum);         // loss accumulation (loose threshold)
    }
  }

  for (int off = 32; off > 0; off >>= 1) lsum += __shfl_down(lsum, off, 64);
  if (lane == 0) wr[w] = lsum;
  __syncthreads();
  if (tid == 0) atomicAdd(loss_acc, (wr[0] + wr[1]) + (wr[2] + wr[3]));
}

// K3: loss = 1.5 * mean((x_q - x)^2), fp32
__global__ void vq_loss_kernel(const float* __restrict__ loss_acc,
                               float* __restrict__ out) {
  if (threadIdx.x == 0) {
    const float m = loss_acc[0] / 8388608.0f;
    out[LOSS_OFF] = m + 0.5f * m;
  }
}

extern "C" void kernel_launch(void* const* d_in, const int* in_sizes, int n_in,
                              void* d_out, int out_size, void* d_ws, size_t ws_size,
                              hipStream_t stream) {
  const float* x  = (const float*)d_in[0];   // [32,256,32,32] fp32
  const float* cb = (const float*)d_in[1];   // [1024,256] fp32
  float* out = (float*)d_out;                // [x_q_st | loss | indices] fp32

  float* esq      = (float*)d_ws;            // 1024 floats
  float* loss_acc = esq + 1024;              // 1 float (zeroed by K0 each call)
  int*   idxbuf   = (int*)(esq + 1040);      // 32768 ints

  hipLaunchKernelGGL(vq_esq_kernel,    dim3(4),    dim3(256), 0, stream, cb, esq, loss_acc);
  hipLaunchKernelGGL(vq_argmin_kernel, dim3(2048), dim3(256), 0, stream, x, cb, esq, idxbuf, out);
  hipLaunchKernelGGL(vq_gather_kernel, dim3(512),  dim3(256), 0, stream, x, cb, idxbuf, loss_acc, out);
  hipLaunchKernelGGL(vq_loss_kernel,   dim3(1),    dim3(64),  0, stream, loss_acc, out);
}